// Round 1
// baseline (393.354 us; speedup 1.0000x reference)
//
#include <hip/hip_runtime.h>
#include <hip/hip_bf16.h>
#include <stdint.h>

// Problem constants (from reference): B=8, S=2048, IN=4096, OUT=64, L=16
#define NB   8
#define NS   2048
#define NIN  4096
#define NOUT 64
#define NL   16

typedef __attribute__((ext_vector_type(8))) short s16x8;  // 8 bf16 = 4 VGPRs
typedef __attribute__((ext_vector_type(4))) float f32x4;  // MFMA accumulator

__device__ __forceinline__ unsigned short f2bf(float f) {
    union { float f; unsigned u; } v; v.f = f;
    unsigned u = v.u + 0x7fffu + ((v.u >> 16) & 1u);  // RNE (inputs are finite)
    return (unsigned short)(u >> 16);
}

__device__ __forceinline__ s16x8 pack8(float4 a, float4 b) {
    s16x8 r;
    r[0] = (short)f2bf(a.x); r[1] = (short)f2bf(a.y);
    r[2] = (short)f2bf(a.z); r[3] = (short)f2bf(a.w);
    r[4] = (short)f2bf(b.x); r[5] = (short)f2bf(b.y);
    r[6] = (short)f2bf(b.z); r[7] = (short)f2bf(b.w);
    return r;
}

// Pre-kernel: weight fp32 [16,64,4096] -> bf16 in workspace. 8 elems/thread.
__global__ __launch_bounds__(256) void convert_w_kernel(const float* __restrict__ w,
                                                        unsigned short* __restrict__ o) {
    size_t i = ((size_t)blockIdx.x * 256 + threadIdx.x) * 8;
    const float4* src = (const float4*)(w + i);
    float4 a = src[0], b = src[1];
    *(s16x8*)(o + i) = pack8(a, b);
}

constexpr int MT  = 32;        // rows per block
constexpr int KT  = 64;        // k per LDS tile
constexpr int NKT = NIN / KT;  // 64 tiles

// Main kernel. WBF16: weight already converted to bf16 in ws (fast path).
// Grid: 512 blocks = 8 batches * 64 m-tiles; block = 256 threads = 4 waves.
// Wave w computes out rows [mt*32, mt*32+32) x cols [w*16, w*16+16).
template <bool WBF16>
__global__ __launch_bounds__(256) void mll_kernel(const float* __restrict__ x,
                                                  const int* __restrict__ ids,
                                                  const void* __restrict__ wsel,
                                                  float* __restrict__ out) {
    // XOR-swizzled x tile, double buffered: [2][32 rows][64 k] bf16 = 8 KB.
    __shared__ __align__(16) unsigned short xs[2 * MT * KT];

    const int bx   = blockIdx.x;
    const int b    = bx >> 6;      // NS/MT = 64 m-tiles per batch
    const int mt   = bx & 63;
    const int aid  = ids[b];
    const int t    = threadIdx.x;
    const int lane = t & 63;
    const int wv   = t >> 6;       // 0..3

    const float* xbase = x + ((size_t)b * NS + (size_t)mt * MT) * NIN;

    // ---- staging coords: thread t loads row (t>>3), 8 contiguous k at (t&7)*8
    const int srow   = t >> 3;     // 0..31
    const int schunk = t & 7;      // 0..7
    const float* gsrc = xbase + (size_t)srow * NIN + schunk * 8;
    // LDS elem offset with XOR swizzle (chunk' = chunk ^ (row&7)) -> conflict-free b128
    const int soff = srow * KT + ((schunk ^ (srow & 7)) * 8);

    // ---- compute coords
    const int l15 = lane & 15;
    const int lk  = lane >> 4;     // 0..3 (k-group)

    // B-fragment global pointers (per-wave n-rows; weight is [OUT][IN] k-major)
    const unsigned short* wb16 = nullptr;
    const float*          wb32 = nullptr;
    if (WBF16) wb16 = (const unsigned short*)wsel + ((size_t)aid * NOUT + wv * 16 + l15) * NIN + lk * 8;
    else       wb32 = (const float*)wsel          + ((size_t)aid * NOUT + wv * 16 + l15) * NIN + lk * 8;

    f32x4 acc0 = {0.f, 0.f, 0.f, 0.f};
    f32x4 acc1 = {0.f, 0.f, 0.f, 0.f};

    // ---- prologue: tile 0 -> LDS buf0; tile 1 -> regs
    {
        const float4* g0 = (const float4*)gsrc;
        float4 c0 = g0[0], c1 = g0[1];
        *(s16x8*)(xs + soff) = pack8(c0, c1);
    }
    const float4* g1 = (const float4*)(gsrc + KT);
    float4 r0 = g1[0], r1 = g1[1];
    __syncthreads();

    for (int tile = 0; tile < NKT; ++tile) {
        const int p = tile & 1;

        // prefetch tile+2 (clamped; tail re-loads last tile, harmless)
        const int pt = (tile + 2 < NKT) ? (tile + 2) : (NKT - 1);
        const float4* gn = (const float4*)(gsrc + (size_t)pt * KT);
        float4 n0 = gn[0], n1 = gn[1];

        const unsigned short* buf = xs + p * (MT * KT);

#pragma unroll
        for (int s = 0; s < 2; ++s) {   // two K=32 MFMA steps per tile
            s16x8 bfrag;
            if (WBF16) {
                bfrag = *(const s16x8*)(wb16 + (size_t)tile * KT + s * 32);
            } else {
                const float4* wp = (const float4*)(wb32 + (size_t)tile * KT + s * 32);
                bfrag = pack8(wp[0], wp[1]);
            }
            const int ae = l15 * KT + (((s * 4 + lk) ^ (l15 & 7)) * 8);
            s16x8 af0 = *(const s16x8*)(buf + ae);            // rows 0..15
            s16x8 af1 = *(const s16x8*)(buf + ae + 16 * KT);  // rows 16..31
            acc0 = __builtin_amdgcn_mfma_f32_16x16x32_bf16(af0, bfrag, acc0, 0, 0, 0);
            acc1 = __builtin_amdgcn_mfma_f32_16x16x32_bf16(af1, bfrag, acc1, 0, 0, 0);
        }

        // write tile+1 (held in r0/r1) into the other buffer
        if (tile + 1 < NKT) {
            *(s16x8*)(xs + (1 - p) * (MT * KT) + soff) = pack8(r0, r1);
        }
        r0 = n0; r1 = n1;
        __syncthreads();
    }

    // ---- epilogue: D layout col = lane&15 (n), row = (lane>>4)*4 + reg (m)
    float* ob = out + ((size_t)b * NS + (size_t)mt * MT) * NOUT + wv * 16 + l15;
    const int rbase = lk * 4;
#pragma unroll
    for (int r = 0; r < 4; ++r) {
        ob[(size_t)(rbase + r) * NOUT]      = acc0[r];
        ob[(size_t)(16 + rbase + r) * NOUT] = acc1[r];
    }
}

extern "C" void kernel_launch(void* const* d_in, const int* in_sizes, int n_in,
                              void* d_out, int out_size, void* d_ws, size_t ws_size,
                              hipStream_t stream) {
    const float* x   = (const float*)d_in[0];
    const int*   ids = (const int*)d_in[1];
    const float* w   = (const float*)d_in[2];
    float*       out = (float*)d_out;

    const size_t wbytes = (size_t)NL * NOUT * NIN * sizeof(unsigned short);  // 8.4 MB
    const int grid = NB * (NS / MT);  // 512

    if (ws_size >= wbytes) {
        unsigned short* wbf = (unsigned short*)d_ws;
        const int n = NL * NOUT * NIN;               // 4,194,304
        convert_w_kernel<<<n / (256 * 8), 256, 0, stream>>>(w, wbf);
        mll_kernel<true><<<grid, 256, 0, stream>>>(x, ids, wbf, out);
    } else {
        mll_kernel<false><<<grid, 256, 0, stream>>>(x, ids, w, out);
    }
}